// Round 4
// baseline (598.358 us; speedup 1.0000x reference)
//
#include <hip/hip_runtime.h>
#include <hip/hip_bf16.h>

// ---------------- problem dims ----------------
constexpr int T_ = 2048;   // B*S tokens
constexpr int H_ = 2048;
constexpr int F_ = 1408;
constexpr int E_ = 8;
constexpr int SF_ = 2816;  // shared intermediate

typedef __bf16 bf16;
typedef bf16 bf16x4 __attribute__((ext_vector_type(4)));
typedef bf16 bf16x8 __attribute__((ext_vector_type(8)));
typedef float f32x4 __attribute__((ext_vector_type(4)));

#define DEVI __device__ __forceinline__

// grid partitions
constexpr int TR_GRID = 5280;            // 128x128 transpose tiles
constexpr int PREP_GRID = TR_GRID + T_;  // + fused gate/route blocks
constexpr int GU_SH = 768;            // shared gate/up part (44 cols padded to 48)
constexpr int GU_EX = 3072;           // expert part (8e x 3colslot x 16rb x 8x)
constexpr int GU_GRID = GU_SH + GU_EX;
constexpr int DNSH_GRID = 512;        // shared down: 32col(x64) x 16rb, direct store
constexpr int DNEX_GRID = 2048;       // expert down: 8e x 2colslot x 16rb x 8x, atomic

// async global->LDS, 16B per lane. LDS dest must be wave-uniform base + lane*16.
// Global source address is PER-LANE (enables fused gather + swizzled source).
DEVI void async16(const void* g, void* l) {
    __builtin_amdgcn_global_load_lds(
        (const __attribute__((address_space(1))) unsigned int*)g,
        (__attribute__((address_space(3))) unsigned int*)l, 16, 0, 0);
}

// ---------------- transpose device part: fp32 [R][C] 128x128 tile -> bf16 [C][R]
// R3 counters: 64x64 tile ran 2.2 TB/s, VALU 7%, conflicts 3% -> HBM transaction-
// granularity bound (256B reads / 128B writes). 128x128 doubles both: 512B-contig
// reads (16 in-flight float4/thread) and 256B-contig writes (16 lanes x 16B on one
// dst row). bf16 in LDS: 128 x 132 = 33.8KB -> 4 blocks/CU.
// Swizzle col' = c ^ (r & 0x7C) (bits 2-6; preserves mod-4 -> 8B-aligned b64 fill).
// Fill bank: (2r + cp>>1) mod 32, 32 lanes span 16 even banks x2 + odd partners
// -> 2/bank, free. Read bank: 16rq+2j+((c0^(j&4))>>1 ^ 4rq)+(d>>1): rq 0..15 ->
// {k,k^4,k^8,k^12}x{0,16} = 8 banks, x2 rq-alias, x2 d -> 16 banks x 4 = 4-way
// (1.58x, LDS pipe floor ~23us, off critical path).
DEVI void transpose_tile(const float* __restrict__ src, bf16* __restrict__ dst,
                         int R, int C, int t, bf16* tile /* 128*132 */) {
    int tiles_c = C >> 7;
    int r0 = (t / tiles_c) * 128, c0 = (t % tiles_c) * 128;
    int th = threadIdx.x;
    int fr = th >> 5;             // 0..7
    int fc = (th & 31) * 4;       // 0..124
#pragma unroll
    for (int p = 0; p < 16; p++) {
        int r = fr + p * 8;
        float4 v = *(const float4*)(src + (size_t)(r0 + r) * C + c0 + fc);
        bf16x4 b;
        b[0] = (bf16)v.x; b[1] = (bf16)v.y; b[2] = (bf16)v.z; b[3] = (bf16)v.w;
        *(bf16x4*)(tile + r * 132 + (fc ^ (r & 0x7C))) = b;
    }
    __syncthreads();
#pragma unroll
    for (int p = 0; p < 8; p++) {
        int ch = p * 256 + th;
        int c = ch >> 4, rq = ch & 15;   // 16 lanes cover one dst row's 256B
        bf16x8 o;
#pragma unroll
        for (int j = 0; j < 8; j++) {
            int row = rq * 8 + j;
            o[j] = tile[row * 132 + (c ^ (row & 0x7C))];
        }
        *(bf16x8*)(dst + (size_t)(c0 + c) * R + r0 + rq * 8) = o;
    }
}

// ---------------- route device part: x fp32->bf16 + gate softmax + top-2 --------
DEVI void gate_route_token(const float* __restrict__ x, const float* __restrict__ gw,
                           bf16* __restrict__ xb, int* __restrict__ cnt,
                           int* __restrict__ list, float* __restrict__ wlist,
                           int t, float* wred /* [4][E_] */) {
    int tid = threadIdx.x;
    const float* xr = x + (size_t)t * H_;
    int h0 = tid * 8;
    float4 a = *(const float4*)(xr + h0);
    float4 b = *(const float4*)(xr + h0 + 4);
    float xv[8] = {a.x, a.y, a.z, a.w, b.x, b.y, b.z, b.w};
    bf16x8 v;
#pragma unroll
    for (int j = 0; j < 8; j++) v[j] = (bf16)xv[j];
    *(bf16x8*)(xb + (size_t)t * H_ + h0) = v;

    float p[E_];
#pragma unroll
    for (int e = 0; e < E_; e++) p[e] = 0.f;
#pragma unroll
    for (int j = 0; j < 8; j++)
#pragma unroll
        for (int e = 0; e < E_; e++) p[e] += xv[j] * gw[e * H_ + h0 + j];
#pragma unroll
    for (int e = 0; e < E_; e++)
#pragma unroll
        for (int off = 32; off > 0; off >>= 1) p[e] += __shfl_down(p[e], off, 64);
    int lane = tid & 63, wid = tid >> 6;
    if (lane == 0)
#pragma unroll
        for (int e = 0; e < E_; e++) wred[wid * E_ + e] = p[e];
    __syncthreads();
    if (tid == 0) {
        float l[E_];
#pragma unroll
        for (int e = 0; e < E_; e++)
            l[e] = wred[0 * E_ + e] + wred[1 * E_ + e] + wred[2 * E_ + e] + wred[3 * E_ + e];
        float mx = l[0];
#pragma unroll
        for (int e = 1; e < E_; e++) mx = fmaxf(mx, l[e]);
        float sc[E_], s = 0.f;
#pragma unroll
        for (int e = 0; e < E_; e++) { sc[e] = __expf(l[e] - mx); s += sc[e]; }
#pragma unroll
        for (int e = 0; e < E_; e++) sc[e] /= s;
        int i1 = 0;
#pragma unroll
        for (int e = 1; e < E_; e++) if (sc[e] > sc[i1]) i1 = e;
        int i2 = (i1 == 0) ? 1 : 0;
#pragma unroll
        for (int e = 0; e < E_; e++) if (e != i1 && sc[e] > sc[i2]) i2 = e;
        int p1 = atomicAdd(&cnt[i1], 1);
        list[i1 * T_ + p1] = t; wlist[i1 * T_ + p1] = sc[i1];
        int p2 = atomicAdd(&cnt[i2], 1);
        list[i2 * T_ + p2] = t; wlist[i2 * T_ + p2] = sc[i2];
    }
}

// ---------------- fused prep: weight transposes + gate/route in one launch ------
// Blocks [0, TR_GRID): 128x128 transpose tiles of the 6 weight tensors.
// Blocks [TR_GRID, TR_GRID+T): per-token convert+route.
__global__ void fused_prep(const float* __restrict__ gp, const float* __restrict__ up,
                           const float* __restrict__ dp, const float* __restrict__ sg,
                           const float* __restrict__ su, const float* __restrict__ sd,
                           bf16* __restrict__ wg, bf16* __restrict__ wu,
                           bf16* __restrict__ wd, bf16* __restrict__ sgt,
                           bf16* __restrict__ sut, bf16* __restrict__ sdt,
                           const float* __restrict__ x, const float* __restrict__ gw,
                           bf16* __restrict__ xb, int* __restrict__ cnt,
                           int* __restrict__ list, float* __restrict__ wlist) {
    __shared__ __align__(16) bf16 tile[128 * 132];   // route path reuses first 128B
    int id = blockIdx.x;
    if (id >= TR_GRID) {
        gate_route_token(x, gw, xb, cnt, list, wlist, id - TR_GRID, (float*)tile);
        return;
    }
    const float* src; bf16* dst; int R, C, t;
    // tile counts: gate/up 8x176, down 8x176, sg/su 352, sd 352
    if (id < 1408)      { int e = id / 176; t = id % 176; R = 2048; C = 1408;
                          src = gp + (size_t)e * R * C; dst = wg + (size_t)e * R * C; }
    else if (id < 2816) { int e = (id - 1408) / 176; t = (id - 1408) % 176; R = 2048; C = 1408;
                          src = up + (size_t)e * R * C; dst = wu + (size_t)e * R * C; }
    else if (id < 4224) { int e = (id - 2816) / 176; t = (id - 2816) % 176; R = 1408; C = 2048;
                          src = dp + (size_t)e * R * C; dst = wd + (size_t)e * R * C; }
    else if (id < 4576) { t = id - 4224; R = 2048; C = 2816; src = sg; dst = sgt; }
    else if (id < 4928) { t = id - 4576; R = 2048; C = 2816; src = su; dst = sut; }
    else                { t = id - 4928; R = 2816; C = 2048; src = sd; dst = sdt; }
    transpose_tile(src, dst, R, C, t, tile);
}

// ---------------- combined gate/up GEMM: act = [w *] silu(A@Bg^T)*(A@Bu^T) --------
// One launch covers shared (M=T,N=SF) and all 8 experts (M=cnt[e],N=F). K=H for all.
// Expert rows are GATHERED during staging via list[] (per-lane global src addr for
// global_load_lds) -- no separate gather kernel / xA buffer.
// XCD swizzle: id&7 = XCD slot; same (source,col) stays on one XCD.
__global__ void gemm_gu(const bf16* __restrict__ xb,
                        const bf16* __restrict__ sgt, const bf16* __restrict__ sut,
                        const bf16* __restrict__ wg, const bf16* __restrict__ wu,
                        bf16* __restrict__ act_sh, bf16* __restrict__ act,
                        const int* __restrict__ cnt, const int* __restrict__ list,
                        const float* __restrict__ wlist) {
    int id = blockIdx.x;
    const bf16 *Bg, *Bu; bf16* C;
    const float* wl = nullptr;
    const int* lstA = nullptr;
    int M, N, row0, col0;
    if (id < GU_SH) {
        int x = id & 7, u = id >> 3;            // u in [0,96)
        int cg = u >> 4, rb = u & 15;
        int col = cg * 8 + x;                   // 0..47, valid <44
        if (col >= 44) return;
        Bg = sgt; Bu = sut; C = act_sh;
        M = T_; N = SF_; row0 = rb * 128; col0 = col * 64;
    } else {
        int id2 = id - GU_SH;
        int x = id2 & 7, u = id2 >> 3;          // u in [0,384)
        int e = u / 48, t2 = u % 48, j = t2 >> 4, rb = t2 & 15;
        int col = ((x - e) & 7) + 8 * j;        // 0..23, valid <22
        if (col >= 22) return;
        M = cnt[e]; row0 = rb * 128;
        if (row0 >= M) return;
        lstA = list + (size_t)e * T_;
        Bg = wg + (size_t)e * F_ * H_;
        Bu = wu + (size_t)e * F_ * H_;
        C = act + (size_t)e * T_ * F_;
        wl = wlist + (size_t)e * T_;
        N = F_; col0 = col * 64;
    }

    __shared__ __align__(16) bf16 As[128 * 64];
    __shared__ __align__(16) bf16 Bgs[64 * 64];
    __shared__ __align__(16) bf16 Bus[64 * 64];

    int tid = threadIdx.x, lane = tid & 63, wid = tid >> 6;
    int wm = (wid >> 1) * 64, wn = (wid & 1) * 32;
    int lm = lane & 15, lq = lane >> 4;

    // per-thread A-staging source rows (kt-invariant): gathered via list for experts
    int srcrow[4];
#pragma unroll
    for (int j = 0; j < 4; j++) {
        int m = (j * 256 + tid) >> 3;
        int gr = row0 + m; if (gr >= M) gr = M - 1;
        srcrow[j] = lstA ? lstA[gr] : gr;
    }

    f32x4 accg[4][2] = {};
    f32x4 accu[4][2] = {};
    constexpr int nkt = H_ >> 6;   // 32

    for (int kt = 0; kt < nkt; kt++) {
        int k0 = kt * 64;
#pragma unroll
        for (int j = 0; j < 4; j++) {          // A tile: 1024 16B chunks
            int L = j * 256 + tid;
            int m = L >> 3, cp = L & 7, c = cp ^ (m & 7);
            async16(xb + (size_t)srcrow[j] * H_ + k0 + c * 8, (void*)(As + L * 8));
        }
#pragma unroll
        for (int j = 0; j < 2; j++) {          // Bg/Bu tiles: 512 chunks each
            int L = j * 256 + tid;
            int n = L >> 3, cp = L & 7, c = cp ^ (n & 7);
            async16(Bg + (size_t)(col0 + n) * H_ + k0 + c * 8, (void*)(Bgs + L * 8));
            async16(Bu + (size_t)(col0 + n) * H_ + k0 + c * 8, (void*)(Bus + L * 8));
        }
        __syncthreads();
#pragma unroll
        for (int kk = 0; kk < 2; kk++) {
            bf16x8 af[4], bgf[2], buf_[2];
            int cc = kk * 4 + lq;
#pragma unroll
            for (int mi = 0; mi < 4; mi++) {
                int r = wm + mi * 16 + lm;
                af[mi] = *(const bf16x8*)(As + r * 64 + ((cc ^ (r & 7)) * 8));
            }
#pragma unroll
            for (int ni = 0; ni < 2; ni++) {
                int r = wn + ni * 16 + lm;
                bgf[ni]  = *(const bf16x8*)(Bgs + r * 64 + ((cc ^ (r & 7)) * 8));
                buf_[ni] = *(const bf16x8*)(Bus + r * 64 + ((cc ^ (r & 7)) * 8));
            }
#pragma unroll
            for (int mi = 0; mi < 4; mi++)
#pragma unroll
                for (int ni = 0; ni < 2; ni++) {
                    accg[mi][ni] = __builtin_amdgcn_mfma_f32_16x16x32_bf16(af[mi], bgf[ni], accg[mi][ni], 0, 0, 0);
                    accu[mi][ni] = __builtin_amdgcn_mfma_f32_16x16x32_bf16(af[mi], buf_[ni], accu[mi][ni], 0, 0, 0);
                }
        }
        __syncthreads();
    }
    // epilogue: [w *] silu(g)*u -> bf16
#pragma unroll
    for (int mi = 0; mi < 4; mi++)
#pragma unroll
        for (int r = 0; r < 4; r++) {
            int gr = row0 + wm + mi * 16 + lq * 4 + r;
            if (gr >= M) continue;
            float wv = wl ? wl[gr] : 1.f;
#pragma unroll
            for (int ni = 0; ni < 2; ni++) {
                int gc = col0 + wn + ni * 16 + lm;
                float g = accg[mi][ni][r], u = accu[mi][ni][r];
                float actv = wv * (g / (1.f + __expf(-g)) * u);
                C[(size_t)gr * N + gc] = (bf16)actv;
            }
        }
}

// ---------------- shared down GEMM: out = act_sh @ sdt^T, DIRECT fp32 store ------
// Covers every (t,h) exactly once -> runs first, expert kernel atomicAdds on top.
// No out memset needed; no atomics on this path. 128x64 tile, K=2816 single pass.
__global__ void gemm_down_sh(const bf16* __restrict__ act_sh, const bf16* __restrict__ sdt,
                             float* __restrict__ out) {
    int id = blockIdx.x;                    // 512 blocks
    int x = id & 7, u = id >> 3;            // u in [0,64)
    int cg = u >> 4, rb = u & 15;
    int col = cg * 8 + x;                   // 0..31
    int row0 = rb * 128, col0 = col * 64;

    __shared__ __align__(16) bf16 As[128 * 64];
    __shared__ __align__(16) bf16 Bs[64 * 64];

    int tid = threadIdx.x, lane = tid & 63, wid = tid >> 6;
    int wm = (wid >> 1) * 64, wn = (wid & 1) * 32;
    int lm = lane & 15, lq = lane >> 4;

    f32x4 acc[4][2] = {};
    constexpr int nkt = SF_ >> 6;   // 44

    for (int kt = 0; kt < nkt; kt++) {
        int k0 = kt * 64;
#pragma unroll
        for (int j = 0; j < 4; j++) {
            int L = j * 256 + tid;
            int m = L >> 3, cp = L & 7, c = cp ^ (m & 7);
            async16(act_sh + (size_t)(row0 + m) * SF_ + k0 + c * 8, (void*)(As + L * 8));
        }
#pragma unroll
        for (int j = 0; j < 2; j++) {
            int L = j * 256 + tid;
            int n = L >> 3, cp = L & 7, c = cp ^ (n & 7);
            async16(sdt + (size_t)(col0 + n) * SF_ + k0 + c * 8, (void*)(Bs + L * 8));
        }
        __syncthreads();
#pragma unroll
        for (int kk = 0; kk < 2; kk++) {
            bf16x8 af[4], bfr[2];
            int cc = kk * 4 + lq;
#pragma unroll
            for (int i = 0; i < 4; i++) {
                int r = wm + i * 16 + lm;
                af[i] = *(const bf16x8*)(As + r * 64 + ((cc ^ (r & 7)) * 8));
            }
#pragma unroll
            for (int ni = 0; ni < 2; ni++) {
                int r = wn + ni * 16 + lm;
                bfr[ni] = *(const bf16x8*)(Bs + r * 64 + ((cc ^ (r & 7)) * 8));
            }
#pragma unroll
            for (int mi = 0; mi < 4; mi++)
#pragma unroll
                for (int ni = 0; ni < 2; ni++)
                    acc[mi][ni] = __builtin_amdgcn_mfma_f32_16x16x32_bf16(af[mi], bfr[ni], acc[mi][ni], 0, 0, 0);
        }
        __syncthreads();
    }
#pragma unroll
    for (int mi = 0; mi < 4; mi++)
#pragma unroll
        for (int r = 0; r < 4; r++) {
            int t = row0 + wm + mi * 16 + lq * 4 + r;
#pragma unroll
            for (int ni = 0; ni < 2; ni++) {
                int gc = col0 + wn + ni * 16 + lm;
                out[(size_t)t * H_ + gc] = acc[mi][ni][r];
            }
        }
}

// ---------------- expert down GEMM: out += act @ wd^T (atomic scatter-add) -------
__global__ void gemm_down_ex(const bf16* __restrict__ act, const bf16* __restrict__ wd,
                             float* __restrict__ out, const int* __restrict__ cnt,
                             const int* __restrict__ list) {
    int id = blockIdx.x;
    int x = id & 7, u = id >> 3;          // u in [0,256)
    int e = u >> 5, t2 = u & 31, j = t2 >> 4, rb = t2 & 15;
    int col = ((x - e) & 7) + 8 * j;      // 0..15
    int M = cnt[e], row0 = rb * 128;
    if (row0 >= M) return;
    const bf16* A = act + (size_t)e * T_ * F_;
    const bf16* B = wd + (size_t)e * H_ * F_;
    const int* lst = list + (size_t)e * T_;
    int col0 = col * 128;

    __shared__ __align__(16) bf16 As[128 * 64];
    __shared__ __align__(16) bf16 Bs[128 * 64];

    int tid = threadIdx.x, lane = tid & 63, wid = tid >> 6;
    int wm = (wid >> 1) * 64, wn = (wid & 1) * 64;
    int lm = lane & 15, lq = lane >> 4;

    f32x4 acc[4][4] = {};
    constexpr int nkt = F_ >> 6;   // 22

    for (int kt = 0; kt < nkt; kt++) {
        int k0 = kt * 64;
#pragma unroll
        for (int j2 = 0; j2 < 4; j2++) {
            int L = j2 * 256 + tid;
            int m = L >> 3, cp = L & 7, c = cp ^ (m & 7);
            int gr = row0 + m; if (gr >= M) gr = M - 1;
            async16(A + (size_t)gr * F_ + k0 + c * 8, (void*)(As + L * 8));
            async16(B + (size_t)(col0 + m) * F_ + k0 + c * 8, (void*)(Bs + L * 8));
        }
        __syncthreads();
#pragma unroll
        for (int kk = 0; kk < 2; kk++) {
            bf16x8 af[4], bfr[4];
            int cc = kk * 4 + lq;
#pragma unroll
            for (int i = 0; i < 4; i++) {
                int ra = wm + i * 16 + lm;
                af[i] = *(const bf16x8*)(As + ra * 64 + ((cc ^ (ra & 7)) * 8));
                int rb2 = wn + i * 16 + lm;
                bfr[i] = *(const bf16x8*)(Bs + rb2 * 64 + ((cc ^ (rb2 & 7)) * 8));
            }
#pragma unroll
            for (int mi = 0; mi < 4; mi++)
#pragma unroll
                for (int ni = 0; ni < 4; ni++)
                    acc[mi][ni] = __builtin_amdgcn_mfma_f32_16x16x32_bf16(af[mi], bfr[ni], acc[mi][ni], 0, 0, 0);
        }
        __syncthreads();
    }
#pragma unroll
    for (int mi = 0; mi < 4; mi++)
#pragma unroll
        for (int r = 0; r < 4; r++) {
            int cr = row0 + wm + mi * 16 + lq * 4 + r;
            if (cr >= M) continue;
            int t = lst[cr];
#pragma unroll
            for (int ni = 0; ni < 4; ni++) {
                int gc = col0 + wn + ni * 16 + lm;
                atomicAdd(&out[(size_t)t * H_ + gc], acc[mi][ni][r]);
            }
        }
}

// ---------------- launch ----------------
extern "C" void kernel_launch(void* const* d_in, const int* in_sizes, int n_in,
                              void* d_out, int out_size, void* d_ws, size_t ws_size,
                              hipStream_t stream) {
    const float* x     = (const float*)d_in[0];
    const float* gw    = (const float*)d_in[1];
    const float* gproj = (const float*)d_in[2];
    const float* uproj = (const float*)d_in[3];
    const float* dproj = (const float*)d_in[4];
    const float* sg    = (const float*)d_in[5];
    const float* su    = (const float*)d_in[6];
    const float* sd    = (const float*)d_in[7];
    float* out = (float*)d_out;

    char* w = (char*)d_ws;
    size_t off = 0;
    auto alloc = [&](size_t bytes) { void* p = w + off; off += (bytes + 255) & ~(size_t)255; return p; };
    bf16* wg_t   = (bf16*)alloc((size_t)E_ * F_ * H_ * 2);   // [E][F][H]
    bf16* wu_t   = (bf16*)alloc((size_t)E_ * F_ * H_ * 2);   // [E][F][H]
    bf16* wd_t   = (bf16*)alloc((size_t)E_ * H_ * F_ * 2);   // [E][H][F]
    bf16* sg_t   = (bf16*)alloc((size_t)SF_ * H_ * 2);       // [SF][H]
    bf16* su_t   = (bf16*)alloc((size_t)SF_ * H_ * 2);       // [SF][H]
    bf16* sd_t   = (bf16*)alloc((size_t)H_ * SF_ * 2);       // [H][SF]
    bf16* xb     = (bf16*)alloc((size_t)T_ * H_ * 2);        // [T][H]
    bf16* act    = (bf16*)alloc((size_t)E_ * T_ * F_ * 2);   // [E][T][F] (w-scaled)
    bf16* act_sh = (bf16*)alloc((size_t)T_ * SF_ * 2);       // [T][SF]
    int*  cnt    = (int*)alloc(256);
    int*  list   = (int*)alloc((size_t)E_ * T_ * 4);
    float* wlist = (float*)alloc((size_t)E_ * T_ * 4);
    (void)ws_size; (void)in_sizes; (void)n_in; (void)out_size;

    hipMemsetAsync(cnt, 0, 256, stream);

    fused_prep<<<PREP_GRID, 256, 0, stream>>>(gproj, uproj, dproj, sg, su, sd,
                                              wg_t, wu_t, wd_t, sg_t, su_t, sd_t,
                                              x, gw, xb, cnt, list, wlist);

    gemm_gu<<<GU_GRID, 256, 0, stream>>>(xb, sg_t, su_t, wg_t, wu_t,
                                         act_sh, act, cnt, list, wlist);
    gemm_down_sh<<<DNSH_GRID, 256, 0, stream>>>(act_sh, sd_t, out);
    gemm_down_ex<<<DNEX_GRID, 256, 0, stream>>>(act, wd_t, out, cnt, list);
}

// Round 7
// 591.842 us; speedup vs baseline: 1.0110x; 1.0110x over previous
//
#include <hip/hip_runtime.h>
#include <hip/hip_bf16.h>

// ---------------- problem dims ----------------
constexpr int T_ = 2048;   // B*S tokens
constexpr int H_ = 2048;
constexpr int F_ = 1408;
constexpr int E_ = 8;
constexpr int SF_ = 2816;  // shared intermediate

typedef __bf16 bf16;
typedef bf16 bf16x4 __attribute__((ext_vector_type(4)));
typedef bf16 bf16x8 __attribute__((ext_vector_type(8)));
typedef float f32x4 __attribute__((ext_vector_type(4)));

#define DEVI __device__ __forceinline__

// grid partitions
constexpr int TR_PREP = 3520;            // gp/up/sg/su 128x128 transpose tiles
constexpr int PREP_GRID = TR_PREP + T_;  // + fused gate/route blocks
constexpr int GU_SH = 768;            // shared gate/up part (44 cols padded to 48)
constexpr int GU_EX = 3072;           // expert part (8e x 3colslot x 16rb x 8x)
constexpr int GU_GRID = GU_SH + GU_EX;
constexpr int TR_GU = 1760;           // dp/sd transpose tiles fused into gu launch
constexpr int GU_GRID_TOT = GU_GRID + TR_GU;
constexpr int DNSH_GRID = 512;        // shared down: 32col(x64) x 16rb, direct store
constexpr int DNEX_GRID = 2048;       // expert down: 8e x 2colslot x 16rb x 8x, atomic

// async global->LDS, 16B per lane. LDS dest must be wave-uniform base + lane*16.
// Global source address is PER-LANE (enables fused gather + swizzled source).
DEVI void async16(const void* g, void* l) {
    __builtin_amdgcn_global_load_lds(
        (const __attribute__((address_space(1))) unsigned int*)g,
        (__attribute__((address_space(3))) unsigned int*)l, 16, 0, 0);
}

// ---------------- transpose device part: fp32 [R][C] 128x128 tile -> bf16 [C][R]
// R4 post-mortem: BW flat at 2.15 TB/s across 64/128 tiles -> fill loop was
// 1-outstanding-load serialized (VGPR=32). Batch 4 float4 loads into named regs
// (static idx, fully unrolled) -> ~4 in flight per wave.
// Swizzle col' = c ^ (r & 0x7C); fill 2-way free, read 4-way (off critical path).
DEVI void transpose_tile(const float* __restrict__ src, bf16* __restrict__ dst,
                         int R, int C, int t, bf16* tile /* 128*132 */) {
    int tiles_c = C >> 7;
    int r0 = (t / tiles_c) * 128, c0 = (t % tiles_c) * 128;
    int th = threadIdx.x;
    int fr = th >> 5;             // 0..7
    int fc = (th & 31) * 4;       // 0..124
#pragma unroll
    for (int p4 = 0; p4 < 4; p4++) {
        float4 v0 = *(const float4*)(src + (size_t)(r0 + fr + (p4 * 4 + 0) * 8) * C + c0 + fc);
        float4 v1 = *(const float4*)(src + (size_t)(r0 + fr + (p4 * 4 + 1) * 8) * C + c0 + fc);
        float4 v2 = *(const float4*)(src + (size_t)(r0 + fr + (p4 * 4 + 2) * 8) * C + c0 + fc);
        float4 v3 = *(const float4*)(src + (size_t)(r0 + fr + (p4 * 4 + 3) * 8) * C + c0 + fc);
        int r;
        bf16x4 b;
        r = fr + (p4 * 4 + 0) * 8;
        b[0] = (bf16)v0.x; b[1] = (bf16)v0.y; b[2] = (bf16)v0.z; b[3] = (bf16)v0.w;
        *(bf16x4*)(tile + r * 132 + (fc ^ (r & 0x7C))) = b;
        r = fr + (p4 * 4 + 1) * 8;
        b[0] = (bf16)v1.x; b[1] = (bf16)v1.y; b[2] = (bf16)v1.z; b[3] = (bf16)v1.w;
        *(bf16x4*)(tile + r * 132 + (fc ^ (r & 0x7C))) = b;
        r = fr + (p4 * 4 + 2) * 8;
        b[0] = (bf16)v2.x; b[1] = (bf16)v2.y; b[2] = (bf16)v2.z; b[3] = (bf16)v2.w;
        *(bf16x4*)(tile + r * 132 + (fc ^ (r & 0x7C))) = b;
        r = fr + (p4 * 4 + 3) * 8;
        b[0] = (bf16)v3.x; b[1] = (bf16)v3.y; b[2] = (bf16)v3.z; b[3] = (bf16)v3.w;
        *(bf16x4*)(tile + r * 132 + (fc ^ (r & 0x7C))) = b;
    }
    __syncthreads();
#pragma unroll
    for (int p = 0; p < 8; p++) {
        int ch = p * 256 + th;
        int c = ch >> 4, rq = ch & 15;   // 16 lanes cover one dst row's 256B
        bf16x8 o;
#pragma unroll
        for (int j = 0; j < 8; j++) {
            int row = rq * 8 + j;
            o[j] = tile[row * 132 + (c ^ (row & 0x7C))];
        }
        *(bf16x8*)(dst + (size_t)(c0 + c) * R + r0 + rq * 8) = o;
    }
}

// ---------------- route device part: x fp32->bf16 + gate softmax + top-2 --------
DEVI void gate_route_token(const float* __restrict__ x, const float* __restrict__ gw,
                           bf16* __restrict__ xb, int* __restrict__ cnt,
                           int* __restrict__ list, float* __restrict__ wlist,
                           int t, float* wred /* [4][E_] */) {
    int tid = threadIdx.x;
    const float* xr = x + (size_t)t * H_;
    int h0 = tid * 8;
    float4 a = *(const float4*)(xr + h0);
    float4 b = *(const float4*)(xr + h0 + 4);
    float xv[8] = {a.x, a.y, a.z, a.w, b.x, b.y, b.z, b.w};
    bf16x8 v;
#pragma unroll
    for (int j = 0; j < 8; j++) v[j] = (bf16)xv[j];
    *(bf16x8*)(xb + (size_t)t * H_ + h0) = v;

    float p[E_];
#pragma unroll
    for (int e = 0; e < E_; e++) p[e] = 0.f;
#pragma unroll
    for (int j = 0; j < 8; j++)
#pragma unroll
        for (int e = 0; e < E_; e++) p[e] += xv[j] * gw[e * H_ + h0 + j];
#pragma unroll
    for (int e = 0; e < E_; e++)
#pragma unroll
        for (int off = 32; off > 0; off >>= 1) p[e] += __shfl_down(p[e], off, 64);
    int lane = tid & 63, wid = tid >> 6;
    if (lane == 0)
#pragma unroll
        for (int e = 0; e < E_; e++) wred[wid * E_ + e] = p[e];
    __syncthreads();
    if (tid == 0) {
        float l[E_];
#pragma unroll
        for (int e = 0; e < E_; e++)
            l[e] = wred[0 * E_ + e] + wred[1 * E_ + e] + wred[2 * E_ + e] + wred[3 * E_ + e];
        float mx = l[0];
#pragma unroll
        for (int e = 1; e < E_; e++) mx = fmaxf(mx, l[e]);
        float sc[E_], s = 0.f;
#pragma unroll
        for (int e = 0; e < E_; e++) { sc[e] = __expf(l[e] - mx); s += sc[e]; }
#pragma unroll
        for (int e = 0; e < E_; e++) sc[e] /= s;
        int i1 = 0;
#pragma unroll
        for (int e = 1; e < E_; e++) if (sc[e] > sc[i1]) i1 = e;
        int i2 = (i1 == 0) ? 1 : 0;
#pragma unroll
        for (int e = 0; e < E_; e++) if (e != i1 && sc[e] > sc[i2]) i2 = e;
        int p1 = atomicAdd(&cnt[i1], 1);
        list[i1 * T_ + p1] = t; wlist[i1 * T_ + p1] = sc[i1];
        int p2 = atomicAdd(&cnt[i2], 1);
        list[i2 * T_ + p2] = t; wlist[i2 * T_ + p2] = sc[i2];
    }
}

// ---------------- fused prep: gate/up/sg/su transposes + gate/route -------------
// dp/sd transposes moved into the gemm_gu launch (overlap with MFMA-bound gu).
__global__ void fused_prep(const float* __restrict__ gp, const float* __restrict__ up,
                           const float* __restrict__ sg, const float* __restrict__ su,
                           bf16* __restrict__ wg, bf16* __restrict__ wu,
                           bf16* __restrict__ sgt, bf16* __restrict__ sut,
                           const float* __restrict__ x, const float* __restrict__ gw,
                           bf16* __restrict__ xb, int* __restrict__ cnt,
                           int* __restrict__ list, float* __restrict__ wlist) {
    __shared__ __align__(16) bf16 tile[128 * 132];   // route path reuses first 128B
    int id = blockIdx.x;
    if (id >= TR_PREP) {
        gate_route_token(x, gw, xb, cnt, list, wlist, id - TR_PREP, (float*)tile);
        return;
    }
    const float* src; bf16* dst; int R, C, t;
    // tile counts: gp 8x176, up 8x176, sg 352, su 352
    if (id < 1408)      { int e = id / 176; t = id % 176; R = 2048; C = 1408;
                          src = gp + (size_t)e * R * C; dst = wg + (size_t)e * R * C; }
    else if (id < 2816) { int e = (id - 1408) / 176; t = (id - 1408) % 176; R = 2048; C = 1408;
                          src = up + (size_t)e * R * C; dst = wu + (size_t)e * R * C; }
    else if (id < 3168) { t = id - 2816; R = 2048; C = 2816; src = sg; dst = sgt; }
    else                { t = id - 3168; R = 2048; C = 2816; src = su; dst = sut; }
    transpose_tile(src, dst, R, C, t, tile);
}

// ---------------- combined gate/up GEMM: act = [w *] silu(A@Bg^T)*(A@Bu^T) --------
// One launch covers shared (M=T,N=SF) and all 8 experts (M=cnt[e],N=F). K=H for all.
// Expert rows are GATHERED during staging via list[] (per-lane global src addr for
// global_load_lds) -- no separate gather kernel / xA buffer.
// Blocks [GU_GRID, GU_GRID+TR_GU): dp/sd 128x128 transpose tiles -- overlapped
// with the MFMA-bound gu blocks (BW headroom), complete before gemm_down_* launch.
// XCD swizzle: id&7 = XCD slot; same (source,col) stays on one XCD.
__global__ void gemm_gu(const bf16* __restrict__ xb,
                        const bf16* __restrict__ sgt, const bf16* __restrict__ sut,
                        const bf16* __restrict__ wg, const bf16* __restrict__ wu,
                        bf16* __restrict__ act_sh, bf16* __restrict__ act,
                        const int* __restrict__ cnt, const int* __restrict__ list,
                        const float* __restrict__ wlist,
                        const float* __restrict__ dp, const float* __restrict__ sd,
                        bf16* __restrict__ wd, bf16* __restrict__ sdt) {
    __shared__ __align__(16) bf16 smem[128 * 132];   // 33792B: union of gu tiles / tr tile
    int id = blockIdx.x;
    if (id >= GU_GRID) {
        int id2 = id - GU_GRID;
        const float* src; bf16* dst; int R, C, t;
        if (id2 < 1408) { int e = id2 / 176; t = id2 % 176; R = 1408; C = 2048;
                          src = dp + (size_t)e * R * C; dst = wd + (size_t)e * R * C; }
        else            { t = id2 - 1408; R = 2816; C = 2048; src = sd; dst = sdt; }
        transpose_tile(src, dst, R, C, t, smem);
        return;
    }
    bf16* As  = smem;                      // 128*64
    bf16* Bgs = smem + 128 * 64;           // 64*64
    bf16* Bus = smem + 128 * 64 + 64 * 64; // 64*64

    const bf16 *Bg, *Bu; bf16* C;
    const float* wl = nullptr;
    const int* lstA = nullptr;
    int M, N, row0, col0;
    if (id < GU_SH) {
        int x = id & 7, u = id >> 3;            // u in [0,96)
        int cg = u >> 4, rb = u & 15;
        int col = cg * 8 + x;                   // 0..47, valid <44
        if (col >= 44) return;
        Bg = sgt; Bu = sut; C = act_sh;
        M = T_; N = SF_; row0 = rb * 128; col0 = col * 64;
    } else {
        int id2 = id - GU_SH;
        int x = id2 & 7, u = id2 >> 3;          // u in [0,384)
        int e = u / 48, t2 = u % 48, j = t2 >> 4, rb = t2 & 15;
        int col = ((x - e) & 7) + 8 * j;        // 0..23, valid <22
        if (col >= 22) return;
        M = cnt[e]; row0 = rb * 128;
        if (row0 >= M) return;
        lstA = list + (size_t)e * T_;
        Bg = wg + (size_t)e * F_ * H_;
        Bu = wu + (size_t)e * F_ * H_;
        C = act + (size_t)e * T_ * F_;
        wl = wlist + (size_t)e * T_;
        N = F_; col0 = col * 64;
    }

    int tid = threadIdx.x, lane = tid & 63, wid = tid >> 6;
    int wm = (wid >> 1) * 64, wn = (wid & 1) * 32;
    int lm = lane & 15, lq = lane >> 4;

    // per-thread A-staging source rows (kt-invariant): gathered via list for experts
    int srcrow[4];
#pragma unroll
    for (int j = 0; j < 4; j++) {
        int m = (j * 256 + tid) >> 3;
        int gr = row0 + m; if (gr >= M) gr = M - 1;
        srcrow[j] = lstA ? lstA[gr] : gr;
    }

    f32x4 accg[4][2] = {};
    f32x4 accu[4][2] = {};
    constexpr int nkt = H_ >> 6;   // 32

    for (int kt = 0; kt < nkt; kt++) {
        int k0 = kt * 64;
#pragma unroll
        for (int j = 0; j < 4; j++) {          // A tile: 1024 16B chunks
            int L = j * 256 + tid;
            int m = L >> 3, cp = L & 7, c = cp ^ (m & 7);
            async16(xb + (size_t)srcrow[j] * H_ + k0 + c * 8, (void*)(As + L * 8));
        }
#pragma unroll
        for (int j = 0; j < 2; j++) {          // Bg/Bu tiles: 512 chunks each
            int L = j * 256 + tid;
            int n = L >> 3, cp = L & 7, c = cp ^ (n & 7);
            async16(Bg + (size_t)(col0 + n) * H_ + k0 + c * 8, (void*)(Bgs + L * 8));
            async16(Bu + (size_t)(col0 + n) * H_ + k0 + c * 8, (void*)(Bus + L * 8));
        }
        __syncthreads();
#pragma unroll
        for (int kk = 0; kk < 2; kk++) {
            bf16x8 af[4], bgf[2], buf_[2];
            int cc = kk * 4 + lq;
#pragma unroll
            for (int mi = 0; mi < 4; mi++) {
                int r = wm + mi * 16 + lm;
                af[mi] = *(const bf16x8*)(As + r * 64 + ((cc ^ (r & 7)) * 8));
            }
#pragma unroll
            for (int ni = 0; ni < 2; ni++) {
                int r = wn + ni * 16 + lm;
                bgf[ni]  = *(const bf16x8*)(Bgs + r * 64 + ((cc ^ (r & 7)) * 8));
                buf_[ni] = *(const bf16x8*)(Bus + r * 64 + ((cc ^ (r & 7)) * 8));
            }
#pragma unroll
            for (int mi = 0; mi < 4; mi++)
#pragma unroll
                for (int ni = 0; ni < 2; ni++) {
                    accg[mi][ni] = __builtin_amdgcn_mfma_f32_16x16x32_bf16(af[mi], bgf[ni], accg[mi][ni], 0, 0, 0);
                    accu[mi][ni] = __builtin_amdgcn_mfma_f32_16x16x32_bf16(af[mi], buf_[ni], accu[mi][ni], 0, 0, 0);
                }
        }
        __syncthreads();
    }
    // epilogue: [w *] silu(g)*u -> bf16
#pragma unroll
    for (int mi = 0; mi < 4; mi++)
#pragma unroll
        for (int r = 0; r < 4; r++) {
            int gr = row0 + wm + mi * 16 + lq * 4 + r;
            if (gr >= M) continue;
            float wv = wl ? wl[gr] : 1.f;
#pragma unroll
            for (int ni = 0; ni < 2; ni++) {
                int gc = col0 + wn + ni * 16 + lm;
                float g = accg[mi][ni][r], u = accu[mi][ni][r];
                float actv = wv * (g / (1.f + __expf(-g)) * u);
                C[(size_t)gr * N + gc] = (bf16)actv;
            }
        }
}

// ---------------- shared down GEMM: out = act_sh @ sdt^T, DIRECT fp32 store ------
// Covers every (t,h) exactly once -> runs first, expert kernel atomicAdds on top.
// No out memset needed; no atomics on this path. 128x64 tile, K=2816 single pass.
__global__ void gemm_down_sh(const bf16* __restrict__ act_sh, const bf16* __restrict__ sdt,
                             float* __restrict__ out) {
    int id = blockIdx.x;                    // 512 blocks
    int x = id & 7, u = id >> 3;            // u in [0,64)
    int cg = u >> 4, rb = u & 15;
    int col = cg * 8 + x;                   // 0..31
    int row0 = rb * 128, col0 = col * 64;

    __shared__ __align__(16) bf16 As[128 * 64];
    __shared__ __align__(16) bf16 Bs[64 * 64];

    int tid = threadIdx.x, lane = tid & 63, wid = tid >> 6;
    int wm = (wid >> 1) * 64, wn = (wid & 1) * 32;
    int lm = lane & 15, lq = lane >> 4;

    f32x4 acc[4][2] = {};
    constexpr int nkt = SF_ >> 6;   // 44

    for (int kt = 0; kt < nkt; kt++) {
        int k0 = kt * 64;
#pragma unroll
        for (int j = 0; j < 4; j++) {
            int L = j * 256 + tid;
            int m = L >> 3, cp = L & 7, c = cp ^ (m & 7);
            async16(act_sh + (size_t)(row0 + m) * SF_ + k0 + c * 8, (void*)(As + L * 8));
        }
#pragma unroll
        for (int j = 0; j < 2; j++) {
            int L = j * 256 + tid;
            int n = L >> 3, cp = L & 7, c = cp ^ (n & 7);
            async16(sdt + (size_t)(col0 + n) * SF_ + k0 + c * 8, (void*)(Bs + L * 8));
        }
        __syncthreads();
#pragma unroll
        for (int kk = 0; kk < 2; kk++) {
            bf16x8 af[4], bfr[2];
            int cc = kk * 4 + lq;
#pragma unroll
            for (int i = 0; i < 4; i++) {
                int r = wm + i * 16 + lm;
                af[i] = *(const bf16x8*)(As + r * 64 + ((cc ^ (r & 7)) * 8));
            }
#pragma unroll
            for (int ni = 0; ni < 2; ni++) {
                int r = wn + ni * 16 + lm;
                bfr[ni] = *(const bf16x8*)(Bs + r * 64 + ((cc ^ (r & 7)) * 8));
            }
#pragma unroll
            for (int mi = 0; mi < 4; mi++)
#pragma unroll
                for (int ni = 0; ni < 2; ni++)
                    acc[mi][ni] = __builtin_amdgcn_mfma_f32_16x16x32_bf16(af[mi], bfr[ni], acc[mi][ni], 0, 0, 0);
        }
        __syncthreads();
    }
#pragma unroll
    for (int mi = 0; mi < 4; mi++)
#pragma unroll
        for (int r = 0; r < 4; r++) {
            int t = row0 + wm + mi * 16 + lq * 4 + r;
#pragma unroll
            for (int ni = 0; ni < 2; ni++) {
                int gc = col0 + wn + ni * 16 + lm;
                out[(size_t)t * H_ + gc] = acc[mi][ni][r];
            }
        }
}

// ---------------- expert down GEMM: out += act @ wd^T (atomic scatter-add) -------
__global__ void gemm_down_ex(const bf16* __restrict__ act, const bf16* __restrict__ wd,
                             float* __restrict__ out, const int* __restrict__ cnt,
                             const int* __restrict__ list) {
    int id = blockIdx.x;
    int x = id & 7, u = id >> 3;          // u in [0,256)
    int e = u >> 5, t2 = u & 31, j = t2 >> 4, rb = t2 & 15;
    int col = ((x - e) & 7) + 8 * j;      // 0..15
    int M = cnt[e], row0 = rb * 128;
    if (row0 >= M) return;
    const bf16* A = act + (size_t)e * T_ * F_;
    const bf16* B = wd + (size_t)e * H_ * F_;
    const int* lst = list + (size_t)e * T_;
    int col0 = col * 128;

    __shared__ __align__(16) bf16 As[128 * 64];
    __shared__ __align__(16) bf16 Bs[128 * 64];

    int tid = threadIdx.x, lane = tid & 63, wid = tid >> 6;
    int wm = (wid >> 1) * 64, wn = (wid & 1) * 64;
    int lm = lane & 15, lq = lane >> 4;

    f32x4 acc[4][4] = {};
    constexpr int nkt = F_ >> 6;   // 22

    for (int kt = 0; kt < nkt; kt++) {
        int k0 = kt * 64;
#pragma unroll
        for (int j2 = 0; j2 < 4; j2++) {
            int L = j2 * 256 + tid;
            int m = L >> 3, cp = L & 7, c = cp ^ (m & 7);
            int gr = row0 + m; if (gr >= M) gr = M - 1;
            async16(A + (size_t)gr * F_ + k0 + c * 8, (void*)(As + L * 8));
            async16(B + (size_t)(col0 + m) * F_ + k0 + c * 8, (void*)(Bs + L * 8));
        }
        __syncthreads();
#pragma unroll
        for (int kk = 0; kk < 2; kk++) {
            bf16x8 af[4], bfr[4];
            int cc = kk * 4 + lq;
#pragma unroll
            for (int i = 0; i < 4; i++) {
                int ra = wm + i * 16 + lm;
                af[i] = *(const bf16x8*)(As + ra * 64 + ((cc ^ (ra & 7)) * 8));
                int rb2 = wn + i * 16 + lm;
                bfr[i] = *(const bf16x8*)(Bs + rb2 * 64 + ((cc ^ (rb2 & 7)) * 8));
            }
#pragma unroll
            for (int mi = 0; mi < 4; mi++)
#pragma unroll
                for (int ni = 0; ni < 4; ni++)
                    acc[mi][ni] = __builtin_amdgcn_mfma_f32_16x16x32_bf16(af[mi], bfr[ni], acc[mi][ni], 0, 0, 0);
        }
        __syncthreads();
    }
#pragma unroll
    for (int mi = 0; mi < 4; mi++)
#pragma unroll
        for (int r = 0; r < 4; r++) {
            int cr = row0 + wm + mi * 16 + lq * 4 + r;
            if (cr >= M) continue;
            int t = lst[cr];
#pragma unroll
            for (int ni = 0; ni < 4; ni++) {
                int gc = col0 + wn + ni * 16 + lm;
                atomicAdd(&out[(size_t)t * H_ + gc], acc[mi][ni][r]);
            }
        }
}

// ---------------- launch ----------------
extern "C" void kernel_launch(void* const* d_in, const int* in_sizes, int n_in,
                              void* d_out, int out_size, void* d_ws, size_t ws_size,
                              hipStream_t stream) {
    const float* x     = (const float*)d_in[0];
    const float* gw    = (const float*)d_in[1];
    const float* gproj = (const float*)d_in[2];
    const float* uproj = (const float*)d_in[3];
    const float* dproj = (const float*)d_in[4];
    const float* sg    = (const float*)d_in[5];
    const float* su    = (const float*)d_in[6];
    const float* sd    = (const float*)d_in[7];
    float* out = (float*)d_out;

    char* w = (char*)d_ws;
    size_t off = 0;
    auto alloc = [&](size_t bytes) { void* p = w + off; off += (bytes + 255) & ~(size_t)255; return p; };
    bf16* wg_t   = (bf16*)alloc((size_t)E_ * F_ * H_ * 2);   // [E][F][H]
    bf16* wu_t   = (bf16*)alloc((size_t)E_ * F_ * H_ * 2);   // [E][F][H]
    bf16* wd_t   = (bf16*)alloc((size_t)E_ * H_ * F_ * 2);   // [E][H][F]
    bf16* sg_t   = (bf16*)alloc((size_t)SF_ * H_ * 2);       // [SF][H]
    bf16* su_t   = (bf16*)alloc((size_t)SF_ * H_ * 2);       // [SF][H]
    bf16* sd_t   = (bf16*)alloc((size_t)H_ * SF_ * 2);       // [H][SF]
    bf16* xb     = (bf16*)alloc((size_t)T_ * H_ * 2);        // [T][H]
    bf16* act    = (bf16*)alloc((size_t)E_ * T_ * F_ * 2);   // [E][T][F] (w-scaled)
    bf16* act_sh = (bf16*)alloc((size_t)T_ * SF_ * 2);       // [T][SF]
    int*  cnt    = (int*)alloc(256);
    int*  list   = (int*)alloc((size_t)E_ * T_ * 4);
    float* wlist = (float*)alloc((size_t)E_ * T_ * 4);
    (void)ws_size; (void)in_sizes; (void)n_in; (void)out_size;

    hipMemsetAsync(cnt, 0, 256, stream);

    fused_prep<<<PREP_GRID, 256, 0, stream>>>(gproj, uproj, sg, su,
                                              wg_t, wu_t, sg_t, su_t,
                                              x, gw, xb, cnt, list, wlist);

    gemm_gu<<<GU_GRID_TOT, 256, 0, stream>>>(xb, sg_t, su_t, wg_t, wu_t,
                                             act_sh, act, cnt, list, wlist,
                                             dproj, sd, wd_t, sd_t);
    gemm_down_sh<<<DNSH_GRID, 256, 0, stream>>>(act_sh, sd_t, out);
    gemm_down_ex<<<DNEX_GRID, 256, 0, stream>>>(act, wd_t, out, cnt, list);
}